// Round 6
// baseline (227.953 us; speedup 1.0000x reference)
//
#include <hip/hip_runtime.h>

// CANet fused kernel, round 11.
// Post-mortem r10: LDS diet to 37.4K (4-block capable) changed NOTHING (occ 30%,
// dur 139us, VGPR 84 flat). Diagnosis: CSV VGPR_Count is ARCH-only; persistent
// live set (w1f16+w2f32+w3f16+b1v/b2v16+taps+addr ~150 total incl AGPR) > 128
// -> HW caps 2 waves/SIMD = ~2 blocks/CU regardless of LDS. r9 corroborates:
// forced 128-total hit 47% occ (4 blocks) but spilled ~50 regs.
// r11: cut 32 persistent regs, THEN force 4 blocks:
//  - w3f -> LDS w3_s[12][128] bf16 (3KB), XOR-swizzled col^((row&7)<<3)
//    (all m-lanes alias mod-32 banks otherwise -> 12-way). m>=12 clamps to
//    row 11 (those lanes' output discarded).
//  - b1v/b2v -> LDS bias_s[256]; accum init via ds_read_b128 per phase
//    (barriers prevent hoisting to permanent regs; intra-phase CSE = 2 reads).
//  - wp_s -> wpT[9][48] (r9's transpose, conflict-free, -576B) so w3_s fits:
//    LDS total 40832B -> exactly 4 blocks/CU.
//  - __launch_bounds__(256,4): persistent set now ~100-110 <= 128 budget.
// Abort signal for this line: FETCH/WRITE jump (= spill).

#define ACT_S 136     // 272 B rows (16B-aligned) for bufA/h1S [px][ch]
#define NOISE_BASE 9437184   // 16*9*65536

// d_ws: shorts [0,26624): w1b[128][64]@0, w2b[128][128]@8192, w3b[16][128]@24576
// floats @ WSF_OFF: bp[48], b1[128], b2[128], wpT[9][48], emb[48]
#define WSF_OFF 13312
#define WSF_BP 0
#define WSF_B1 48
#define WSF_B2 176
#define WSF_WP 304
#define WSF_EMB 736

typedef short bf16x8 __attribute__((ext_vector_type(8)));
typedef float f32x4 __attribute__((ext_vector_type(4)));

__device__ __forceinline__ short f2bf(float f) {
    union { float f; unsigned u; } cv; cv.f = f;
    unsigned r = cv.u + 0x7FFFu + ((cv.u >> 16) & 1u);
    return (short)(r >> 16);
}
// pack two fp32 -> dword of two bf16 (round-half-up): lo16=bf(f0), hi16=bf(f1)
__device__ __forceinline__ unsigned pk2bf(float f0, float f1) {
    union { float f; unsigned u; } a, b; a.f = f0; b.f = f1;
    return __builtin_amdgcn_perm(b.u + 0x8000u, a.u + 0x8000u, 0x07060302u);
}

// ---------------- weight prep + time embedding (one launch) ----------------
__global__ void prep_emb_kernel(const float* __restrict__ wpg, const float* __restrict__ bpg,
                                const float* __restrict__ w1g, const float* __restrict__ b1g,
                                const float* __restrict__ w2g, const float* __restrict__ b2g,
                                const float* __restrict__ w3g,
                                const int* __restrict__ t,
                                const float* __restrict__ wt, const float* __restrict__ bt,
                                short* __restrict__ wsb, float* __restrict__ wsf)
{
    if (blockIdx.x < 107) {
        int i = blockIdx.x * 256 + threadIdx.x;
        if (i < 8192) {                       // w1 [128][48] -> [128][64] pad
            int o = i >> 6, c = i & 63;
            wsb[i] = (c < 48) ? f2bf(w1g[o * 48 + c]) : (short)0;
        } else if (i < 24576) {               // w2 [128][128]
            wsb[i] = f2bf(w2g[i - 8192]);
        } else if (i < 26624) {               // w3 [12][128] -> [16][128] pad
            int k = i - 24576;
            wsb[i] = (k < 1536) ? f2bf(w3g[k]) : (short)0;
        } else if (i < 26672) {
            wsf[WSF_BP + (i - 26624)] = bpg[i - 26624];
        } else if (i < 26800) {
            wsf[WSF_B1 + (i - 26672)] = b1g[i - 26672];
        } else if (i < 26928) {
            wsf[WSF_B2 + (i - 26800)] = b2g[i - 26800];
        } else if (i < 27360) {
            int idx = i - 26928;              // wp transpose: [oc][k] -> [k][oc]
            int oc = idx / 9, k = idx % 9;
            wsf[WSF_WP + k * 48 + oc] = wpg[idx];
        }
        return;
    }
    int b = blockIdx.x - 107;
    int lane = threadIdx.x;
    if (lane >= 64) return;
    float tv = (float)t[b];
    float s0 = 0.f, s1 = 0.f, s2 = 0.f;
    const float LOG1E4 = 9.210340371976184f;
    #pragma unroll
    for (int ii = 0; ii < 2; ++ii) {
        int i = lane + ii * 64;
        float invf = __expf(-LOG1E4 * (float)i * (1.0f / 128.0f));
        float ang = tv * invf;
        float sn = sinf(ang), cs = cosf(ang);
        float ss = sn / (1.0f + __expf(-sn));
        float sc = cs / (1.0f + __expf(-cs));
        s0 += ss * wt[0 * 256 + i] + sc * wt[0 * 256 + i + 128];
        s1 += ss * wt[1 * 256 + i] + sc * wt[1 * 256 + i + 128];
        s2 += ss * wt[2 * 256 + i] + sc * wt[2 * 256 + i + 128];
    }
    #pragma unroll
    for (int off = 32; off; off >>= 1) {
        s0 += __shfl_down(s0, off);
        s1 += __shfl_down(s1, off);
        s2 += __shfl_down(s2, off);
    }
    if (lane == 0) {
        wsf[WSF_EMB + b * 3 + 0] = s0 + bt[0];
        wsf[WSF_EMB + b * 3 + 1] = s1 + bt[1];
        wsf[WSF_EMB + b * 3 + 2] = s2 + bt[2];
    }
}

// ---------------- main fused kernel ----------------
// MFMA 16x16x32 (m89): A lane(i=lane&15,q) holds A[i][q*8+j]; B symmetric:
// lane holds B[q*8+j][i]. D: col(N)=lane&15, row(M)=q*4+r.
// bufA timeline per iter: conv writes perc (cols 0..63) -> B1 -> G1 reads perc,
// writes h1S -> B2 -> G2 reads h1S, writes h2 (cols 0..127 of bufA) -> B3 ->
// G3 reads bufA -> B4 -> next iter's conv overwrites bufA.
__global__ __launch_bounds__(256, 4) void canet_main(
    const float* __restrict__ xg,   // (16,3,256,256)
    const float* __restrict__ hg,   // (16,9,256,256)
    const short* __restrict__ wsb,
    const float* __restrict__ wsf,
    float* __restrict__ outg)
{
    __shared__ __align__(16) short bufA[64 * ACT_S];   // perc (cols<64) / h2
    __shared__ __align__(16) short h1S[64 * ACT_S];
    __shared__ __align__(16) short w3_s[12 * 128];     // [oc][k], col XOR-swizzled
    __shared__ __align__(16) float wpT_s[9 * 48];      // [k][oc]
    __shared__ __align__(16) float bias_s[256];        // b1 @0, b2 @128
    __shared__ __align__(16) float bp_s[48];

    const int tid = threadIdx.x;
    const int b = blockIdx.x >> 8;
    const int y = blockIdx.x & 255;

    for (int i = tid; i < 432; i += 256) wpT_s[i] = wsf[WSF_WP + i];
    if (tid < 48) bp_s[tid] = wsf[WSF_BP + tid];
    bias_s[tid] = wsf[WSF_B1 + tid];                   // b1[0:128], b2[128:256]
    for (int i = tid; i < 1536; i += 256) {            // w3 [12][128] swizzled
        int row = i >> 7, col = i & 127;
        w3_s[(row << 7) + (col ^ ((row & 7) << 3))] = wsb[24576 + i];
    }

    const int wv = tid >> 6;
    const int lane = tid & 63;
    const int m = lane & 15;
    const int q = lane >> 4;

    // ---- persistent weight fragments (w1, w2 only; 48 regs) ----
    bf16x8 w1f[2][2], w2f[2][4];
    #pragma unroll
    for (int j = 0; j < 2; ++j) {
        int n = wv * 32 + j * 16 + m;
        #pragma unroll
        for (int ks = 0; ks < 2; ++ks)
            w1f[j][ks] = *(const bf16x8*)(wsb + n * 64 + ks * 32 + q * 8);
        #pragma unroll
        for (int ks = 0; ks < 4; ++ks)
            w2f[j][ks] = *(const bf16x8*)(wsb + 8192 + n * 128 + ks * 32 + q * 8);
    }
    const float embv = (m < 3) ? wsf[WSF_EMB + b * 3 + m] : 0.0f;

    // conv source pointers (lane's 3 input channels: ic = 3q + i3)
    const float* src3[3];
    #pragma unroll
    for (int i3 = 0; i3 < 3; ++i3) {
        int ic = 3 * q + i3;
        src3[i3] = (ic < 3) ? (xg + (((size_t)b * 3 + ic) << 16))
                            : (hg + (((size_t)b * 9 + (ic - 3)) << 16));
    }

    const int mm = (m < 12) ? m : 11;        // w3 row clamp (lanes 12-15 discarded)
    const int w3sw = (mm & 7) << 3;

    __syncthreads();   // staged LDS ready

    for (int it = 0; it < 4; ++it) {
        const int x0 = it * 64;
        const int px = x0 + wv * 16 + m;

        // ---- depthwise 3x3 conv -> bufA[px][ch<48] + pad ----
        {
            const int xm1 = px - (px > 0);
            const int xp1 = px + (px < 255);
            const bool okl = (px > 0), okr = (px < 255);
            short* prow = bufA + (wv * 16 + m) * ACT_S;
            const bool interior = (y >= 1) && (y <= 254);
            #pragma unroll
            for (int i3 = 0; i3 < 3; ++i3) {
                const float* s = src3[i3];
                float tap[9];
                if (interior) {
                    #pragma unroll
                    for (int ky = 0; ky < 3; ++ky) {
                        const float* rp = s + (y + ky - 1) * 256;
                        float c0 = rp[xm1], c1 = rp[px], c2 = rp[xp1];
                        tap[ky * 3 + 0] = okl ? c0 : 0.0f;
                        tap[ky * 3 + 1] = c1;
                        tap[ky * 3 + 2] = okr ? c2 : 0.0f;
                    }
                } else {
                    #pragma unroll
                    for (int ky = 0; ky < 3; ++ky) {
                        int yy = y + ky - 1;
                        bool yok = (yy >= 0) && (yy < 256);
                        const float* rp = s + (yok ? yy : y) * 256;
                        float c0 = rp[xm1], c1 = rp[px], c2 = rp[xp1];
                        tap[ky * 3 + 0] = (yok && okl) ? c0 : 0.0f;
                        tap[ky * 3 + 1] = yok ? c1 : 0.0f;
                        tap[ky * 3 + 2] = (yok && okr) ? c2 : 0.0f;
                    }
                }
                f32x4 a4 = *(const f32x4*)(bp_s + 12 * q + 4 * i3);
                #pragma unroll
                for (int k = 0; k < 9; ++k) {
                    f32x4 w4 = *(const f32x4*)(wpT_s + k * 48 + 12 * q + 4 * i3);
                    float t = tap[k];
                    a4[0] += w4[0] * t; a4[1] += w4[1] * t;
                    a4[2] += w4[2] * t; a4[3] += w4[3] * t;
                }
                uint2 pk;
                pk.x = pk2bf(a4[0], a4[1]);
                pk.y = pk2bf(a4[2], a4[3]);
                *(uint2*)(prow + 12 * q + 4 * i3) = pk;
            }
            *(uint2*)(prow + 48 + 4 * q) = uint2{0u, 0u};   // K pad 48..63 (G2 clobbers)
        }
        __syncthreads();   // B1: perc ready

        // ---- GEMM1 (swapped): D[ch][px] = w1 . perc^T ; write h1S[px][ch] ----
        #pragma unroll
        for (int nt = 0; nt < 4; ++nt) {
            f32x4 c0 = *(const f32x4*)(bias_s + wv * 32 + q * 4);
            f32x4 c1 = *(const f32x4*)(bias_s + wv * 32 + 16 + q * 4);
            #pragma unroll
            for (int ks = 0; ks < 2; ++ks) {
                bf16x8 p = *(const bf16x8*)(bufA + (nt * 16 + m) * ACT_S + ks * 32 + q * 8);
                c0 = __builtin_amdgcn_mfma_f32_16x16x32_bf16(w1f[0][ks], p, c0, 0, 0, 0);
                c1 = __builtin_amdgcn_mfma_f32_16x16x32_bf16(w1f[1][ks], p, c1, 0, 0, 0);
            }
            short* drow = h1S + (nt * 16 + m) * ACT_S + wv * 32 + q * 4;
            uint2 pk;
            pk.x = pk2bf(fmaxf(c0[0], 0.f), fmaxf(c0[1], 0.f));
            pk.y = pk2bf(fmaxf(c0[2], 0.f), fmaxf(c0[3], 0.f));
            *(uint2*)drow = pk;
            pk.x = pk2bf(fmaxf(c1[0], 0.f), fmaxf(c1[1], 0.f));
            pk.y = pk2bf(fmaxf(c1[2], 0.f), fmaxf(c1[3], 0.f));
            *(uint2*)(drow + 16) = pk;
        }
        __syncthreads();   // B2: h1 ready; perc fully read

        // ---- GEMM2 (swapped): D[ch][px] = w2 . h1^T ; write h2 -> bufA ----
        #pragma unroll
        for (int nt = 0; nt < 4; ++nt) {
            f32x4 c0 = *(const f32x4*)(bias_s + 128 + wv * 32 + q * 4);
            f32x4 c1 = *(const f32x4*)(bias_s + 128 + wv * 32 + 16 + q * 4);
            #pragma unroll
            for (int ks = 0; ks < 4; ++ks) {
                bf16x8 a = *(const bf16x8*)(h1S + (nt * 16 + m) * ACT_S + ks * 32 + q * 8);
                c0 = __builtin_amdgcn_mfma_f32_16x16x32_bf16(w2f[0][ks], a, c0, 0, 0, 0);
                c1 = __builtin_amdgcn_mfma_f32_16x16x32_bf16(w2f[1][ks], a, c1, 0, 0, 0);
            }
            short* drow = bufA + (nt * 16 + m) * ACT_S + wv * 32 + q * 4;
            uint2 pk;
            pk.x = pk2bf(fmaxf(c0[0], 0.f), fmaxf(c0[1], 0.f));
            pk.y = pk2bf(fmaxf(c0[2], 0.f), fmaxf(c0[3], 0.f));
            *(uint2*)drow = pk;
            pk.x = pk2bf(fmaxf(c1[0], 0.f), fmaxf(c1[1], 0.f));
            pk.y = pk2bf(fmaxf(c1[2], 0.f), fmaxf(c1[3], 0.f));
            *(uint2*)(drow + 16) = pk;
        }
        __syncthreads();   // B3: h2 ready

        // ---- GEMM3: out = h2 . w3^T ; D col=oc, row=px; float4 store ----
        {
            f32x4 acc = {0.f, 0.f, 0.f, 0.f};
            #pragma unroll
            for (int ks = 0; ks < 4; ++ks) {
                bf16x8 a = *(const bf16x8*)(bufA + (wv * 16 + m) * ACT_S + ks * 32 + q * 8);
                bf16x8 w3k = *(const bf16x8*)(w3_s + (mm << 7) + ((ks * 32 + q * 8) ^ w3sw));
                acc = __builtin_amdgcn_mfma_f32_16x16x32_bf16(a, w3k, acc, 0, 0, 0);
            }
            if (m < 12) {
                int xx0 = x0 + wv * 16 + q * 4;
                size_t idx;
                if (m < 3) {
                    idx = (size_t)NOISE_BASE + (((size_t)b * 3 + m) << 16) + (size_t)y * 256 + xx0;
                } else {
                    idx = (((size_t)b * 9 + (m - 3)) << 16) + (size_t)y * 256 + xx0;
                }
                f32x4 vst = {acc[0] + embv, acc[1] + embv, acc[2] + embv, acc[3] + embv};
                *(f32x4*)(outg + idx) = vst;
            }
        }
        __syncthreads();   // B4: bufA fully read; next conv may overwrite
    }
}

extern "C" void kernel_launch(void* const* d_in, const int* in_sizes, int n_in,
                              void* d_out, int out_size, void* d_ws, size_t ws_size,
                              hipStream_t stream) {
    const float* xg  = (const float*)d_in[0];
    const float* hg  = (const float*)d_in[1];
    const int*   tg  = (const int*)  d_in[2];
    const float* wpg = (const float*)d_in[3];
    const float* bpg = (const float*)d_in[4];
    const float* w1g = (const float*)d_in[5];
    const float* b1g = (const float*)d_in[6];
    const float* w2g = (const float*)d_in[7];
    const float* b2g = (const float*)d_in[8];
    const float* w3g = (const float*)d_in[9];
    const float* wtg = (const float*)d_in[10];
    const float* btg = (const float*)d_in[11];
    float* outg = (float*)d_out;
    short* wsb  = (short*)d_ws;
    float* wsf  = (float*)d_ws + WSF_OFF;

    prep_emb_kernel<<<123, 256, 0, stream>>>(wpg, bpg, w1g, b1g, w2g, b2g, w3g,
                                             tg, wtg, btg, wsb, wsf);
    canet_main<<<4096, 256, 0, stream>>>(xg, hg, wsb, wsf, outg);
}